// Round 6
// baseline (314.148 us; speedup 1.0000x reference)
//
#include <hip/hip_runtime.h>
#include <hip/hip_bf16.h>
#include <cstdint>
#include <cstddef>

// Problem constants
#define MROWS 8192   // B*L
#define EDIM  1024   // E
#define VDIM  64     // V
#define NTRI  2016   // V*(V-1)/2
#define NTC   2176   // NTRI + 64 (theta logits) padded to 17*128 tiles

typedef _Float16 half8  __attribute__((ext_vector_type(8)));
typedef _Float16 half4v __attribute__((ext_vector_type(4)));
typedef float    floatx4 __attribute__((ext_vector_type(4)));

typedef __attribute__((address_space(1))) void gvoid;
typedef __attribute__((address_space(3))) void svoid;

__device__ inline void gld_lds16(const _Float16* g, _Float16* l) {
    // async global->LDS, 16B per lane; LDS dest = wave-uniform base + lane*16
    __builtin_amdgcn_global_load_lds((gvoid*)g, (svoid*)l, 16, 0, 0);
}

#define MFMA16(a, b, c) __builtin_amdgcn_mfma_f32_16x16x32_f16((a), (b), (c), 0, 0, 0)

// Fast erf: Abramowitz-Stegun 7.1.26, |err| < 1.5e-7 (hw v_exp_f32)
__device__ inline float fast_erf(float x) {
    float ax = fabsf(x);
    float t = 1.0f / (1.0f + 0.3275911f * ax);
    float p = t * (0.254829592f +
              t * (-0.284496736f +
              t * (1.421413741f +
              t * (-1.453152027f +
              t * 1.061405429f))));
    float r = 1.0f - p * __expf(-ax * ax);
    return copysignf(r, x);
}

// Fast softplus via hw v_exp/v_log; exact identity, stable both tails
__device__ inline float fast_softplus(float x) {
    return fmaxf(x, 0.0f) + __logf(1.0f + __expf(-fabsf(x)));
}

// ---------------- single fused cast fp32 -> fp16 (3 segments) ----------------
__global__ __launch_bounds__(256) void cast_all(const float* __restrict__ hx,
                                                const float* __restrict__ Wd,
                                                const float* __restrict__ WT,
                                                const float* __restrict__ wt,
                                                _Float16* __restrict__ A_h,
                                                _Float16* __restrict__ Wd_h,
                                                _Float16* __restrict__ Wc_h) {
    const int b = blockIdx.x;
    float4 v;
    _Float16* dst;
    int idx;
    if (b < 8192) {
        idx = (b * 256 + threadIdx.x) * 4;
        v = *(const float4*)(hx + idx);
        dst = A_h;
    } else if (b < 9216) {
        idx = ((b - 8192) * 256 + threadIdx.x) * 4;
        v = *(const float4*)(Wd + idx);
        dst = Wd_h;
    } else {
        idx = ((b - 9216) * 256 + threadIdx.x) * 4;
        if (idx < NTRI * EDIM)                  v = *(const float4*)(WT + idx);
        else if (idx < (NTRI + VDIM) * EDIM)    v = *(const float4*)(wt + (idx - NTRI * EDIM));
        else                                    v = make_float4(0.f, 0.f, 0.f, 0.f);
        dst = Wc_h;
    }
    half4v o;
    o[0] = (_Float16)v.x; o[1] = (_Float16)v.y;
    o[2] = (_Float16)v.z; o[3] = (_Float16)v.w;
    *(half4v*)(dst + idx) = o;
}

// ---------------- GEMM: C = epilogue(A @ Bt^T), fp16 output ----------------
// 8-PHASE schedule (T2+T3+T4+T5 port, m201 family), BM=256 BN=128 BK=64,
// 512 threads = 8 waves (2m x 4n; per-wave C = 128x32). NT = 16 K-tiles,
// 2 K-tiles per main iteration (buf0/buf1), 8 phases per iteration:
//   phase = { ds_read A-band (+B at quadrant 0) | stage 1 half-tile |
//             s_barrier | setprio(1) 8xMFMA setprio(0) | [vmcnt] s_barrier }
// Counted vmcnt(2) ONLY at phases 3 and 7 (never 0 in steady state).
// Half-tile staging schedule (iter i, tiles t0=2i buf0 / t1=2i+1 buf1):
//   ph0: A(t1)h0  ph1: A(t1)h1  ph2: B(t0+2)h0  ph3: B(t0+2)h1 +vmcnt(2)
//   ph4: A(t0+2)h0 ph5: A(t0+2)h1 ph6: B(t1+2)h0 ph7: B(t1+2)h1 +vmcnt(2)
// Deadlines verified: consumption at ph0/ph4 always >= 2 loads behind the
// vmcnt(2) horizon. LDS 2 x (A 32KB + B 16KB) = 96KB -> 1 block/CU; the
// phase interleave (not TLP) hides latency, per m201/m233.
//
// Swizzle (both-sides, rule 21): LDS rows of 64 halfs (128B, 8 chunks of
// 16B); slot (r, c) holds global chunk c ^ (r&7); stage pre-swizzles the
// per-lane GLOBAL source (LDS dest lane-pinned linear); reads invert.
// 16-lane b128 read phases touch 8 distinct chunks -> 2-way on banks (free).
//
// Grid 1D: xcd = b&7, slot = b>>3, m-tile = xcd + 8*(slot/ntg), n = slot%ntg.
template <int MODE>
__global__ __launch_bounds__(512, 2) void gemm256(const _Float16* __restrict__ A,
                                                  const _Float16* __restrict__ Bt,
                                                  const float* __restrict__ bias,
                                                  const float* __restrict__ bias2,
                                                  _Float16* __restrict__ C,
                                                  int ldC, int ntg) {
    __shared__ __align__(16) _Float16 S[2][24576];   // [buf][A 16384 | B 8192]

    const int tid  = threadIdx.x;
    const int xcd  = blockIdx.x & 7;
    const int slot = blockIdx.x >> 3;
    const int mg   = slot / ntg;
    const int nn   = slot - mg * ntg;
    const int m0   = (xcd + mg * 8) * 256;
    const int n0   = nn * 128;

    const int w = tid >> 6, lane = tid & 63;
    const int wr = w >> 2;                 // 0..1 -> 128 rows
    const int wc = w & 3;                  // 0..3 -> 32 cols
    const int lrow = lane & 15, lquad = lane >> 4;

    floatx4 acc[8][2] = {};

    // ---- stage geometry: thread t -> row seg*64 + (t>>3), chunk c0 = t&7
    const int sr = tid >> 3;               // 0..63
    const int sc = tid & 7;
    const int gk = (sc ^ (sr & 7)) * 8;    // pre-swizzled global k-offset
    const _Float16* pA = A  + (size_t)(m0 + sr) * EDIM + gk;
    const _Float16* pB = Bt + (size_t)(n0 + sr) * EDIM + gk;

    // ---- read geometry: chunk xor = row&7 = lrow&7 (rows step by 16)
    const int k0off = ( lquad      ^ (lrow & 7)) * 8;   // kstep 0 (k 0..31)
    const int k1off = ((4 + lquad) ^ (lrow & 7)) * 8;   // kstep 1 (k 32..63)
    const int abase = (wr * 128 + lrow) * 64;           // + i*1024
    const int bbase = 16384 + (wc * 32 + lrow) * 64;    // + j*1024

    auto stA = [&](int buf, int kt, int seg) {          // seg 0..3 (64 rows)
        gld_lds16(pA + (size_t)seg * 64 * EDIM + kt * 64,
                  &S[buf][seg * 4096 + tid * 8]);
    };
    auto stB = [&](int buf, int kt, int seg) {          // seg 0..1 (64 rows)
        gld_lds16(pB + (size_t)seg * 64 * EDIM + kt * 64,
                  &S[buf][16384 + seg * 4096 + tid * 8]);
    };

    half8 bf[4];
    auto loadB = [&](const _Float16* Sb) {              // all j, both ksteps
        bf[0] = *(const half8*)(Sb + bbase + k0off);
        bf[1] = *(const half8*)(Sb + bbase + k1off);
        bf[2] = *(const half8*)(Sb + bbase + 1024 + k0off);
        bf[3] = *(const half8*)(Sb + bbase + 1024 + k1off);
    };

#define PHASE(SB, P, STAGE_STMT, TAIL_STMT)                                   \
    {                                                                         \
        const _Float16* Sb_ = (SB);                                           \
        half8 a00 = *(const half8*)(Sb_ + abase + (2*(P))*1024   + k0off);    \
        half8 a01 = *(const half8*)(Sb_ + abase + (2*(P))*1024   + k1off);    \
        half8 a10 = *(const half8*)(Sb_ + abase + (2*(P)+1)*1024 + k0off);    \
        half8 a11 = *(const half8*)(Sb_ + abase + (2*(P)+1)*1024 + k1off);    \
        STAGE_STMT;                                                           \
        asm volatile("" ::: "memory");                                        \
        __builtin_amdgcn_s_barrier();                                         \
        asm volatile("" ::: "memory");                                        \
        __builtin_amdgcn_s_setprio(1);                                        \
        acc[2*(P)][0]   = MFMA16(a00, bf[0], acc[2*(P)][0]);                  \
        acc[2*(P)][0]   = MFMA16(a01, bf[1], acc[2*(P)][0]);                  \
        acc[2*(P)][1]   = MFMA16(a00, bf[2], acc[2*(P)][1]);                  \
        acc[2*(P)][1]   = MFMA16(a01, bf[3], acc[2*(P)][1]);                  \
        acc[2*(P)+1][0] = MFMA16(a10, bf[0], acc[2*(P)+1][0]);                \
        acc[2*(P)+1][0] = MFMA16(a11, bf[1], acc[2*(P)+1][0]);                \
        acc[2*(P)+1][1] = MFMA16(a10, bf[2], acc[2*(P)+1][1]);                \
        acc[2*(P)+1][1] = MFMA16(a11, bf[3], acc[2*(P)+1][1]);                \
        __builtin_amdgcn_s_setprio(0);                                        \
        TAIL_STMT;                                                            \
        asm volatile("" ::: "memory");                                        \
        __builtin_amdgcn_s_barrier();                                         \
        asm volatile("" ::: "memory");                                        \
    }

    // ---- prologue: A(0), B(0), B(1); wait A0+B0 (B1's 2 loads in flight)
    stA(0, 0, 0); stA(0, 0, 1); stA(0, 0, 2); stA(0, 0, 3);
    stB(0, 0, 0); stB(0, 0, 1);
    stB(1, 1, 0); stB(1, 1, 1);
    asm volatile("s_waitcnt vmcnt(2)" ::: "memory");
    __builtin_amdgcn_s_barrier();
    asm volatile("" ::: "memory");

#pragma unroll 1
    for (int it = 0; it < 8; ++it) {
        const int t0 = 2 * it, t1 = 2 * it + 1;
        const bool st = (it < 7);
        const _Float16* S0 = S[0];
        const _Float16* S1 = S[1];

        // ---- K-tile t0 (buf0), phases 0-3
        loadB(S0);
        PHASE(S0, 0, { stA(1, t1, 0); stA(1, t1, 1); }, {});
        PHASE(S0, 1, { stA(1, t1, 2); stA(1, t1, 3); }, {});
        PHASE(S0, 2, { if (st) stB(0, t0 + 2, 0); }, {});
        PHASE(S0, 3, { if (st) stB(0, t0 + 2, 1); },
              { if (st) asm volatile("s_waitcnt vmcnt(2)" ::: "memory");
                else    asm volatile("s_waitcnt vmcnt(0)" ::: "memory"); });

        // ---- K-tile t1 (buf1), phases 4-7
        loadB(S1);
        PHASE(S1, 0, { if (st) { stA(0, t0 + 2, 0); stA(0, t0 + 2, 1); } }, {});
        PHASE(S1, 1, { if (st) { stA(0, t0 + 2, 2); stA(0, t0 + 2, 3); } }, {});
        PHASE(S1, 2, { if (st) stB(1, t1 + 2, 0); }, {});
        PHASE(S1, 3, { if (st) stB(1, t1 + 2, 1); },
              { if (st) asm volatile("s_waitcnt vmcnt(2)" ::: "memory"); });
    }
#undef PHASE

    // Epilogue. C/D layout (m89-verified): col = lane&15, row = (lane>>4)*4 + reg
    const int cm = m0 + wr * 128 + lquad * 4;
    const int cn = n0 + wc * 32 + lrow;
#pragma unroll
    for (int j = 0; j < 2; ++j) {
        const int gn = cn + j * 16;
        float bv;
        if (MODE == 0) {
            bv = bias[gn];
        } else {
            // 16-aligned col groups; NTRI, NTRI+64 are multiples of 16
            if (gn < NTRI)             bv = bias[gn];
            else if (gn < NTRI + VDIM) bv = bias2[gn - NTRI];
            else                       bv = 0.0f;
        }
#pragma unroll
        for (int i = 0; i < 8; ++i) {
#pragma unroll
            for (int r = 0; r < 4; ++r) {
                float x = acc[i][j][r] + bv;
                float y;
                if (MODE == 0) {
                    y = 0.5f * x * (1.0f + fast_erf(x * 0.70710678118654752f));
                } else {
                    if (gn < NTRI)             y = fast_softplus(x);
                    else if (gn < NTRI + VDIM) y = x;      // raw pi logit
                    else                       y = 0.0f;   // padding
                }
                C[(size_t)(cm + i * 16 + r) * ldC + gn] = (_Float16)y;
            }
        }
    }
}

// ---------------- LayerNorm: fp16 G in -> fp16 Hh out ----------------
__global__ __launch_bounds__(256) void ln_kernel(const _Float16* __restrict__ G,
                                                 const float* __restrict__ gw,
                                                 const float* __restrict__ bw,
                                                 _Float16* __restrict__ Hh) {
    const int row = blockIdx.x, tid = threadIdx.x;
    half4v v = ((const half4v*)(G + (size_t)row * EDIM))[tid];
    float x0 = (float)v[0], x1 = (float)v[1], x2 = (float)v[2], x3 = (float)v[3];
    float s  = x0 + x1 + x2 + x3;
    float ss = x0 * x0 + x1 * x1 + x2 * x2 + x3 * x3;
#pragma unroll
    for (int off = 32; off; off >>= 1) {
        s  += __shfl_down(s, off);
        ss += __shfl_down(ss, off);
    }
    __shared__ float red[8];
    const int w = tid >> 6, lane = tid & 63;
    if (lane == 0) { red[w] = s; red[4 + w] = ss; }
    __syncthreads();
    const float st  = red[0] + red[1] + red[2] + red[3];
    const float sst = red[4] + red[5] + red[6] + red[7];
    const float mu  = st * (1.0f / EDIM);
    const float rs  = 1.0f / sqrtf(sst * (1.0f / EDIM) - mu * mu + 1e-5f);
    float4 gg = ((const float4*)gw)[tid];
    float4 bb = ((const float4*)bw)[tid];
    half4v h4;
    h4[0] = (_Float16)((x0 - mu) * rs * gg.x + bb.x);
    h4[1] = (_Float16)((x1 - mu) * rs * gg.y + bb.y);
    h4[2] = (_Float16)((x2 - mu) * rs * gg.z + bb.z);
    h4[3] = (_Float16)((x3 - mu) * rs * gg.w + bb.w);
    ((half4v*)(Hh + (size_t)row * EDIM))[tid] = h4;
}

// ---------------- Q build + fused softmax: one block per (b,l) row ---------
__global__ __launch_bounds__(256) void q_kernel(const _Float16* __restrict__ Theta,
                                                float* __restrict__ pi_out,
                                                float* __restrict__ Q) {
    const int row = blockIdx.x;
    const int tid = threadIdx.x;
    __shared__ float Th[NTRI];
    __shared__ float spv[VDIM];
    const _Float16* trow = Theta + (size_t)row * NTC;
    if (tid < 252) {  // 252 * 8 = 2016 = NTRI exactly
        half8 h = *(const half8*)(trow + tid * 8);
#pragma unroll
        for (int u = 0; u < 8; ++u) Th[tid * 8 + u] = (float)h[u];
    }
    if (tid >= 192) {  // wave 3: softmax over the 64 logits
        const int lane = tid & 63;
        float lg = (float)trow[NTRI + lane];
        float m = lg;
#pragma unroll
        for (int off = 32; off; off >>= 1) m = fmaxf(m, __shfl_xor(m, off));
        float e = __expf(lg - m);
        float ssum = e;
#pragma unroll
        for (int off = 32; off; off >>= 1) ssum += __shfl_xor(ssum, off);
        float p = e / ssum;
        pi_out[(size_t)row * VDIM + lane] = p;
        spv[lane] = sqrtf(p);
    }
    __syncthreads();

    const int i = tid >> 2;   // Q row 0..63
    const int q = tid & 3;    // col quarter
    const float rpi = 1.0f / spv[i];
    float vals[16];
    float psum = 0.f;
#pragma unroll
    for (int c = 0; c < 16; ++c) {
        const int j = q * 16 + c;
        float out = 0.f;
        if (j != i) {
            const int a = (i < j) ? i : j;
            const int b = (i < j) ? j : i;
            const int t = a * (127 - a) / 2 + (b - a - 1);
            out = Th[t] * spv[j] * rpi;
            psum += out;
        }
        vals[c] = out;
    }
    psum += __shfl_xor(psum, 1);
    psum += __shfl_xor(psum, 2);
    if ((i >> 4) == q) vals[i & 15] = -psum;   // fold diagonal into the store

    float* qrow = Q + ((size_t)row * VDIM + i) * VDIM + q * 16;
    float4* dst = (float4*)qrow;
    dst[0] = make_float4(vals[0], vals[1], vals[2], vals[3]);
    dst[1] = make_float4(vals[4], vals[5], vals[6], vals[7]);
    dst[2] = make_float4(vals[8], vals[9], vals[10], vals[11]);
    dst[3] = make_float4(vals[12], vals[13], vals[14], vals[15]);
}

// ---------------- orchestration ----------------
extern "C" void kernel_launch(void* const* d_in, const int* in_sizes, int n_in,
                              void* d_out, int out_size, void* d_ws, size_t ws_size,
                              hipStream_t stream) {
    const float* hx      = (const float*)d_in[0];
    const float* W_dense = (const float*)d_in[1];
    const float* b_dense = (const float*)d_in[2];
    const float* ln_g    = (const float*)d_in[3];
    const float* ln_b    = (const float*)d_in[4];
    const float* W_theta = (const float*)d_in[5];
    const float* b_theta = (const float*)d_in[6];
    const float* W_Theta = (const float*)d_in[7];
    const float* b_Theta = (const float*)d_in[8];

    uint8_t* ws = (uint8_t*)d_ws;
    _Float16* A_h  = (_Float16*)ws;                          // 16 MB (hx fp16; later h fp16)
    _Float16* Wd_h = (_Float16*)(ws + (size_t)16 * 1048576); //  2 MB
    _Float16* Wc_h = (_Float16*)(ws + (size_t)18 * 1048576); //  4.25 MB (2176x1024)
    _Float16* G_h  = (_Float16*)(ws + (size_t)23 * 1048576); // 16 MB (gelu out, fp16)
    _Float16* Th_h = (_Float16*)(ws + (size_t)23 * 1048576); // 35.7 MB (8192x2176 fp16)

    float* Q_out  = (float*)d_out;                 // 8192*64*64
    float* pi_out = (float*)d_out + (size_t)MROWS * VDIM * VDIM;

    // 1) all fp32->fp16 casts in ONE kernel (8192 + 1024 + 2176 blocks)
    cast_all<<<11392, 256, 0, stream>>>(hx, W_dense, W_Theta, W_theta,
                                        A_h, Wd_h, Wc_h);

    // 2) dense GEMM + gelu -> G_h.  256x128 tiles: 32m x 8n = 256 blocks (1/CU)
    gemm256<0><<<256, 512, 0, stream>>>(A_h, Wd_h, b_dense, nullptr, G_h, EDIM, 8);

    // 3) LayerNorm: fp16 G -> fp16 h into A_h
    ln_kernel<<<MROWS, 256, 0, stream>>>(G_h, ln_g, ln_b, A_h);

    // 4) theta GEMM: 256x128 tiles: 32m x 17n = 544 blocks, single launch
    gemm256<1><<<544, 512, 0, stream>>>(A_h, Wc_h, b_Theta, b_theta, Th_h, NTC, 17);

    // 5) Q assembly + fused softmax
    q_kernel<<<MROWS, 256, 0, stream>>>(Th_h, pi_out, Q_out);
}

// Round 8
// 304.344 us; speedup vs baseline: 1.0322x; 1.0322x over previous
//
#include <hip/hip_runtime.h>
#include <hip/hip_bf16.h>
#include <cstdint>
#include <cstddef>

// Problem constants
#define MROWS 8192   // B*L
#define EDIM  1024   // E
#define VDIM  64     // V
#define NTRI  2016   // V*(V-1)/2
#define NTC   2176   // NTRI + 64 (theta logits) padded to 17*128 tiles

typedef _Float16 half8  __attribute__((ext_vector_type(8)));
typedef _Float16 half4v __attribute__((ext_vector_type(4)));
typedef float    floatx4 __attribute__((ext_vector_type(4)));

typedef __attribute__((address_space(1))) void gvoid;
typedef __attribute__((address_space(3))) void svoid;

__device__ inline void gld_lds16(const _Float16* g, _Float16* l) {
    // async global->LDS, 16B per lane; LDS dest = wave-uniform base + lane*16
    __builtin_amdgcn_global_load_lds((gvoid*)g, (svoid*)l, 16, 0, 0);
}

#define MFMA16(a, b, c) __builtin_amdgcn_mfma_f32_16x16x32_f16((a), (b), (c), 0, 0, 0)

// Fast erf: Abramowitz-Stegun 7.1.26, |err| < 1.5e-7 (hw v_exp_f32)
__device__ inline float fast_erf(float x) {
    float ax = fabsf(x);
    float t = 1.0f / (1.0f + 0.3275911f * ax);
    float p = t * (0.254829592f +
              t * (-0.284496736f +
              t * (1.421413741f +
              t * (-1.453152027f +
              t * 1.061405429f))));
    float r = 1.0f - p * __expf(-ax * ax);
    return copysignf(r, x);
}

// Fast softplus via hw v_exp/v_log; exact identity, stable both tails
__device__ inline float fast_softplus(float x) {
    return fmaxf(x, 0.0f) + __logf(1.0f + __expf(-fabsf(x)));
}

// ---------------- single fused cast fp32 -> fp16 (3 segments) ----------------
__global__ __launch_bounds__(256) void cast_all(const float* __restrict__ hx,
                                                const float* __restrict__ Wd,
                                                const float* __restrict__ WT,
                                                const float* __restrict__ wt,
                                                _Float16* __restrict__ A_h,
                                                _Float16* __restrict__ Wd_h,
                                                _Float16* __restrict__ Wc_h) {
    const int b = blockIdx.x;
    float4 v;
    _Float16* dst;
    int idx;
    if (b < 8192) {
        idx = (b * 256 + threadIdx.x) * 4;
        v = *(const float4*)(hx + idx);
        dst = A_h;
    } else if (b < 9216) {
        idx = ((b - 8192) * 256 + threadIdx.x) * 4;
        v = *(const float4*)(Wd + idx);
        dst = Wd_h;
    } else {
        idx = ((b - 9216) * 256 + threadIdx.x) * 4;
        if (idx < NTRI * EDIM)                  v = *(const float4*)(WT + idx);
        else if (idx < (NTRI + VDIM) * EDIM)    v = *(const float4*)(wt + (idx - NTRI * EDIM));
        else                                    v = make_float4(0.f, 0.f, 0.f, 0.f);
        dst = Wc_h;
    }
    half4v o;
    o[0] = (_Float16)v.x; o[1] = (_Float16)v.y;
    o[2] = (_Float16)v.z; o[3] = (_Float16)v.w;
    *(half4v*)(dst + idx) = o;
}

// ---------------- GEMM body: C = epilogue(A @ Bt^T), fp16 output ----------
// R5's PROVEN 3-buffer counted-vmcnt schedule, widened: 128 x (BNF*64) tile,
// 512 threads = 8 waves (2m x 4n; per-wave 64m x BNF*16n). Per-wave inner
// body is identical to R5's (4 af + BNF bf ds_reads, 4*BNF MFMA, acc[4][BNF])
// but each barrier amortizes over 8 waves and LDS 3 x 24KB = 72KB gives
// 2 blocks/CU = 16 waves/CU (R5: 12).  Main loop NEVER drains vmcnt to 0
// (except t=NT-2); tile t+2 staged while tile t computes.
//
// Swizzle (both-sides, rule 21, carried from R5): rows of 32 halfs (64B,
// 4 chunks of 16B); slot (r,c) holds global chunk c ^ ((r>>1)&3); staging
// pre-swizzles the per-lane GLOBAL source (LDS dest lane-pinned linear);
// reads invert -> 2-way on banks (free, m136).
//
// Grid mapping (local bidx): xcd = bidx&7, slot = bidx>>3,
// m-tile = xcd + 8*(slot/ntg), n = slot%ntg. Same-m blocks share an XCD.
template <int MODE, int BNF>   // BNF: B n-frags/wave. 4 -> BN=256, 2 -> BN=128
__device__ inline void gemm_body(const _Float16* __restrict__ A,
                                 const _Float16* __restrict__ Bt,
                                 const float* __restrict__ bias,
                                 const float* __restrict__ bias2,
                                 _Float16* __restrict__ C,
                                 int ldC, int ntg, int bidx, int col0,
                                 _Float16 (*S)[12288]) {
    constexpr int NT = EDIM / 32;          // 32 K-tiles
    constexpr int BN = BNF * 64;

    const int tid  = threadIdx.x;          // 0..511
    const int xcd  = bidx & 7;
    const int slot = bidx >> 3;
    const int mg   = slot / ntg;
    const int nn   = slot - mg * ntg;
    const int m0   = (xcd + mg * 8) * 128;
    const int n0   = col0 + nn * BN;

    const int w = tid >> 6, lane = tid & 63;
    const int wr = w >> 2, wc = w & 3;         // 2m x 4n waves
    const int lrow = lane & 15, lquad = lane >> 4;

    floatx4 acc[4][BNF] = {};

    // staging: thread t -> row r0 = t>>2 (0..127), chunk c0 = t&3.
    // LDS dest (lane-pinned) = (r0, c0); global chunk = c0 ^ ((r0>>1)&3).
    const int r0 = tid >> 2;
    const int c0 = tid & 3;
    const int gk = (c0 ^ ((r0 >> 1) & 3)) * 8; // swizzled k-offset (halfs)
    const _Float16* Ag  = A  + (size_t)(m0 + r0) * EDIM + gk;
    const _Float16* Bg0 = Bt + (size_t)(n0 + r0) * EDIM + gk;
    const _Float16* Bg1 = Bg0 + (size_t)128 * EDIM;    // BNF==4 only

    // read geometry: chunk xor depends only on lrow (rows step by 16)
    const int xr   = (lrow >> 1) & 3;
    const int koff = (lquad ^ xr) * 8;
    const int aoff = (wr * 64 + lrow) * 32 + koff;              // frag i: +i*512
    const int boff = 4096 + (wc * (BNF * 16) + lrow) * 32 + koff; // frag j: +j*512

    auto stage = [&](int buf, int kt) {
        const int ko = kt * 32;
        gld_lds16(Ag + ko, &S[buf][tid * 8]);
        gld_lds16(Bg0 + ko, &S[buf][4096 + tid * 8]);
        if constexpr (BNF == 4) gld_lds16(Bg1 + ko, &S[buf][8192 + tid * 8]);
    };

    // prologue: stage tiles 0,1; wait tile 0 (tile 1's loads may stay out)
    stage(0, 0);
    stage(1, 1);
    if constexpr (BNF == 4) asm volatile("s_waitcnt vmcnt(3)" ::: "memory");
    else                    asm volatile("s_waitcnt vmcnt(2)" ::: "memory");
    __builtin_amdgcn_s_barrier();

    int buf = 0, sbuf = 2;                    // compute buffer / stage buffer
#pragma unroll 1
    for (int t = 0; t < NT; ++t) {
        const _Float16* Sb = S[buf];
        if (t + 2 < NT) stage(sbuf, t + 2);   // issue early (T3 recipe)

        half8 af[4], bf[BNF];
#pragma unroll
        for (int i = 0; i < 4; ++i)   af[i] = *(const half8*)(Sb + aoff + i * 512);
#pragma unroll
        for (int j = 0; j < BNF; ++j) bf[j] = *(const half8*)(Sb + boff + j * 512);

        __builtin_amdgcn_s_setprio(1);
#pragma unroll
        for (int i = 0; i < 4; ++i)
#pragma unroll
            for (int j = 0; j < BNF; ++j)
                acc[i][j] = MFMA16(af[i], bf[j], acc[i][j]);
        __builtin_amdgcn_s_setprio(0);

        // tile boundary: counted wait -> tile t+1 resident; never drain to 0
        if (t < NT - 2) {
            if constexpr (BNF == 4) asm volatile("s_waitcnt vmcnt(3)" ::: "memory");
            else                    asm volatile("s_waitcnt vmcnt(2)" ::: "memory");
        } else if (t == NT - 2) {
            asm volatile("s_waitcnt vmcnt(0)" ::: "memory");
        }
        if (t < NT - 1) {
            asm volatile("" ::: "memory");
            __builtin_amdgcn_s_barrier();
            asm volatile("" ::: "memory");
        }
        buf  = (buf  == 2) ? 0 : buf + 1;
        sbuf = (sbuf == 2) ? 0 : sbuf + 1;
    }

    // Epilogue (m89-verified C/D layout: col=lane&15, row=(lane>>4)*4+reg)
    const int cm = m0 + wr * 64 + lquad * 4;
    const int cn = n0 + wc * (BNF * 16) + lrow;
#pragma unroll
    for (int j = 0; j < BNF; ++j) {
        const int gn = cn + j * 16;
        float bv;
        if (MODE == 0) {
            bv = bias[gn];
        } else {
            // 16-aligned col groups; NTRI, NTRI+64 are multiples of 16
            if (gn < NTRI)             bv = bias[gn];
            else if (gn < NTRI + VDIM) bv = bias2[gn - NTRI];
            else                       bv = 0.0f;
        }
#pragma unroll
        for (int i = 0; i < 4; ++i) {
#pragma unroll
            for (int r = 0; r < 4; ++r) {
                float x = acc[i][j][r] + bv;
                float y;
                if (MODE == 0) {
                    y = 0.5f * x * (1.0f + fast_erf(x * 0.70710678118654752f));
                } else {
                    if (gn < NTRI)             y = fast_softplus(x);
                    else if (gn < NTRI + VDIM) y = x;      // raw pi logit
                    else                       y = 0.0f;   // padding
                }
                C[(size_t)(cm + i * 16 + r) * ldC + gn] = (_Float16)y;
            }
        }
    }
}

// Wrapper: blocks [0,nwide) run BN=256 over cols [0, ntgW*256);
// blocks [nwide, ...) run BN=128 over cols [col0N, col0N + ntgN*128).
template <int MODE>
__global__ __launch_bounds__(512, 4) void gemmw(const _Float16* __restrict__ A,
                                                const _Float16* __restrict__ Bt,
                                                const float* __restrict__ bias,
                                                const float* __restrict__ bias2,
                                                _Float16* __restrict__ C,
                                                int ldC, int ntgW, int nwide,
                                                int ntgN, int col0N) {
    __shared__ __align__(16) _Float16 S[3][12288];   // 72 KB (A 8KB | B 16KB) x3
    if ((int)blockIdx.x < nwide) {
        gemm_body<MODE, 4>(A, Bt, bias, bias2, C, ldC, ntgW, blockIdx.x, 0, S);
    } else {
        gemm_body<MODE, 2>(A, Bt, bias, bias2, C, ldC, ntgN,
                           blockIdx.x - nwide, col0N, S);
    }
}

// ---------------- LayerNorm: fp16 G in -> fp16 Hh out ----------------
__global__ __launch_bounds__(256) void ln_kernel(const _Float16* __restrict__ G,
                                                 const float* __restrict__ gw,
                                                 const float* __restrict__ bw,
                                                 _Float16* __restrict__ Hh) {
    const int row = blockIdx.x, tid = threadIdx.x;
    half4v v = ((const half4v*)(G + (size_t)row * EDIM))[tid];
    float x0 = (float)v[0], x1 = (float)v[1], x2 = (float)v[2], x3 = (float)v[3];
    float s  = x0 + x1 + x2 + x3;
    float ss = x0 * x0 + x1 * x1 + x2 * x2 + x3 * x3;
#pragma unroll
    for (int off = 32; off; off >>= 1) {
        s  += __shfl_down(s, off);
        ss += __shfl_down(ss, off);
    }
    __shared__ float red[8];
    const int w = tid >> 6, lane = tid & 63;
    if (lane == 0) { red[w] = s; red[4 + w] = ss; }
    __syncthreads();
    const float st  = red[0] + red[1] + red[2] + red[3];
    const float sst = red[4] + red[5] + red[6] + red[7];
    const float mu  = st * (1.0f / EDIM);
    const float rs  = 1.0f / sqrtf(sst * (1.0f / EDIM) - mu * mu + 1e-5f);
    float4 gg = ((const float4*)gw)[tid];
    float4 bb = ((const float4*)bw)[tid];
    half4v h4;
    h4[0] = (_Float16)((x0 - mu) * rs * gg.x + bb.x);
    h4[1] = (_Float16)((x1 - mu) * rs * gg.y + bb.y);
    h4[2] = (_Float16)((x2 - mu) * rs * gg.z + bb.z);
    h4[3] = (_Float16)((x3 - mu) * rs * gg.w + bb.w);
    ((half4v*)(Hh + (size_t)row * EDIM))[tid] = h4;
}

// ---------------- Q build + fused softmax: one block per (b,l) row ---------
__global__ __launch_bounds__(256) void q_kernel(const _Float16* __restrict__ Theta,
                                                float* __restrict__ pi_out,
                                                float* __restrict__ Q) {
    const int row = blockIdx.x;
    const int tid = threadIdx.x;
    __shared__ float Th[NTRI];
    __shared__ float spv[VDIM];
    const _Float16* trow = Theta + (size_t)row * NTC;
    if (tid < 252) {  // 252 * 8 = 2016 = NTRI exactly
        half8 h = *(const half8*)(trow + tid * 8);
#pragma unroll
        for (int u = 0; u < 8; ++u) Th[tid * 8 + u] = (float)h[u];
    }
    if (tid >= 192) {  // wave 3: softmax over the 64 logits
        const int lane = tid & 63;
        float lg = (float)trow[NTRI + lane];
        float m = lg;
#pragma unroll
        for (int off = 32; off; off >>= 1) m = fmaxf(m, __shfl_xor(m, off));
        float e = __expf(lg - m);
        float ssum = e;
#pragma unroll
        for (int off = 32; off; off >>= 1) ssum += __shfl_xor(ssum, off);
        float p = e / ssum;
        pi_out[(size_t)row * VDIM + lane] = p;
        spv[lane] = sqrtf(p);
    }
    __syncthreads();

    const int i = tid >> 2;   // Q row 0..63
    const int q = tid & 3;    // col quarter
    const float rpi = 1.0f / spv[i];
    float vals[16];
    float psum = 0.f;
#pragma unroll
    for (int c = 0; c < 16; ++c) {
        const int j = q * 16 + c;
        float out = 0.f;
        if (j != i) {
            const int a = (i < j) ? i : j;
            const int b = (i < j) ? j : i;
            const int t = a * (127 - a) / 2 + (b - a - 1);
            out = Th[t] * spv[j] * rpi;
            psum += out;
        }
        vals[c] = out;
    }
    psum += __shfl_xor(psum, 1);
    psum += __shfl_xor(psum, 2);
    if ((i >> 4) == q) vals[i & 15] = -psum;   // fold diagonal into the store

    float* qrow = Q + ((size_t)row * VDIM + i) * VDIM + q * 16;
    float4* dst = (float4*)qrow;
    dst[0] = make_float4(vals[0], vals[1], vals[2], vals[3]);
    dst[1] = make_float4(vals[4], vals[5], vals[6], vals[7]);
    dst[2] = make_float4(vals[8], vals[9], vals[10], vals[11]);
    dst[3] = make_float4(vals[12], vals[13], vals[14], vals[15]);
}

// ---------------- orchestration ----------------
extern "C" void kernel_launch(void* const* d_in, const int* in_sizes, int n_in,
                              void* d_out, int out_size, void* d_ws, size_t ws_size,
                              hipStream_t stream) {
    const float* hx      = (const float*)d_in[0];
    const float* W_dense = (const float*)d_in[1];
    const float* b_dense = (const float*)d_in[2];
    const float* ln_g    = (const float*)d_in[3];
    const float* ln_b    = (const float*)d_in[4];
    const float* W_theta = (const float*)d_in[5];
    const float* b_theta = (const float*)d_in[6];
    const float* W_Theta = (const float*)d_in[7];
    const float* b_Theta = (const float*)d_in[8];

    uint8_t* ws = (uint8_t*)d_ws;
    _Float16* A_h  = (_Float16*)ws;                          // 16 MB (hx fp16; later h fp16)
    _Float16* Wd_h = (_Float16*)(ws + (size_t)16 * 1048576); //  2 MB
    _Float16* Wc_h = (_Float16*)(ws + (size_t)18 * 1048576); //  4.25 MB (2176x1024)
    _Float16* G_h  = (_Float16*)(ws + (size_t)23 * 1048576); // 16 MB (gelu out, fp16)
    _Float16* Th_h = (_Float16*)(ws + (size_t)23 * 1048576); // 35.7 MB (8192x2176 fp16)

    float* Q_out  = (float*)d_out;                 // 8192*64*64
    float* pi_out = (float*)d_out + (size_t)MROWS * VDIM * VDIM;

    // 1) all fp32->fp16 casts in ONE kernel (8192 + 1024 + 2176 blocks)
    cast_all<<<11392, 256, 0, stream>>>(hx, W_dense, W_Theta, W_theta,
                                        A_h, Wd_h, Wc_h);

    // 2) dense GEMM + gelu -> G_h.  128x256 tiles: 64m x 4n = 256 blocks (all wide)
    gemmw<0><<<256, 512, 0, stream>>>(A_h, Wd_h, b_dense, nullptr, G_h,
                                      EDIM, 4, 256, 0, 0);

    // 3) LayerNorm: fp16 G -> fp16 h into A_h
    ln_kernel<<<MROWS, 256, 0, stream>>>(G_h, ln_g, ln_b, A_h);

    // 4) theta GEMM, single launch: 512 wide blocks (cols 0..2048, 128x256)
    //    + 64 narrow blocks (cols 2048..2176, 128x128) = 576 blocks
    gemmw<1><<<576, 512, 0, stream>>>(A_h, Wc_h, b_Theta, b_theta, Th_h,
                                      NTC, 8, 512, 1, 2048);

    // 5) Q assembly + fused softmax
    q_kernel<<<MROWS, 256, 0, stream>>>(Th_h, pi_out, Q_out);
}